// Round 5
// baseline (551.215 us; speedup 1.0000x reference)
//
#include <hip/hip_runtime.h>
#include <cstdint>

#pragma clang fp contract(off)

#define TPB 256
typedef unsigned int uint32;
typedef unsigned short u16;
typedef unsigned long long u64;

constexpr int BB = 256;    // batch
constexpr int NN = 8732;   // boxes
constexpr int CC = 21;     // classes
constexpr int KK = 200;    // top-k
constexpr int CH = (NN + TPB - 1) / TPB;   // 35 contiguous elems per thread (index order)
constexpr uint32 KBIAS = 0x3C23D70Au;      // bits(0.01f); kk = bits(p)-KBIAS in [1, 0x35C28F6]

// ---------------- fast f64 exp (fast path only; guarded by interval check) ----------------
__device__ __forceinline__ double fexp(double a) {
  const double L2E = 1.4426950408889634074;
  const double SHIFT = 6755399441055744.0;  // 1.5*2^52
  double t = __builtin_fma(a, L2E, SHIFT);
  int i = (int)__double_as_longlong(t);
  double n = t - SHIFT;
  double r = __builtin_fma(n, -6.93147180369123816490e-01, a);
  r = __builtin_fma(n, -1.90821492927058770002e-10, r);
  double p = 1.6059043836821614599e-10;
  p = __builtin_fma(p, r, 2.0876756987868098979e-9);
  p = __builtin_fma(p, r, 2.5052108385441718775e-8);
  p = __builtin_fma(p, r, 2.7557319223985890653e-7);
  p = __builtin_fma(p, r, 2.7557319223985890653e-6);
  p = __builtin_fma(p, r, 2.4801587301587301587e-5);
  p = __builtin_fma(p, r, 1.9841269841269841270e-4);
  p = __builtin_fma(p, r, 1.3888888888888888889e-3);
  p = __builtin_fma(p, r, 8.3333333333333333333e-3);
  p = __builtin_fma(p, r, 4.1666666666666666667e-2);
  p = __builtin_fma(p, r, 1.6666666666666666667e-1);
  p = __builtin_fma(p, r, 0.5);
  p = __builtin_fma(p, r, 1.0);
  p = __builtin_fma(p, r, 1.0);
  return p * __longlong_as_double((long long)(1023 + i) << 52);
}

// f32(exp(x)) via fexp with libm fallback when the f64 result sits within 65536
// f64-ulps of an f32 rounding boundary (fexp vs libm differ by << that margin).
__device__ __forceinline__ float exp_f32_exact(float xf) {
  double v = fexp((double)xf);
  uint32 low29 = (uint32)__double_as_longlong(v) & 0x1FFFFFFFu;
  uint32 dist = (low29 > 0x10000000u) ? (low29 - 0x10000000u) : (0x10000000u - low29);
  if (__builtin_expect(dist <= 65536u, 0)) v = exp((double)xf);
  return (float)v;
}

// ---------------- shared memory ----------------
struct NmsS {
  alignas(16) float bx1[256];
  alignas(16) float by1[256];
  alignas(16) float bx2[256];
  alignas(16) float by2[256];
  alignas(16) float barea[256];
  alignas(16) float bscore[256];
  // column-major IoU mask: maskT[c*9 + w] bit b = "row 32w+b suppresses col c".
  // u32[9] row pitch (36B): walk loads at lane-stride 9 words -> 2-way bank alias
  // only (gcd(9,32)=1), which is free. Words are ZERO-initialized; units overwrite
  // only valid (row<col) ranges, so below-diagonal bits are provably 0.
  alignas(16) uint32 maskT[256 * 9];
  u64 kept[4];
};
struct SmemT {
  union alignas(16) UU {
    u16 s16[NN];   // 17464 B (select phase; 16-bit bucket keys)
    NmsS nms;      // 15392 B (NMS phase)
  } u;
  // hist's liveness (incl. rare-fallback refinement scans) ends before the first
  // cand write in every path -> safe union; saves 2 KB -> 8 blocks/CU.
  union alignas(16) HC {
    uint32 hist[512];
    u64 cand[256];
  } hc;
  uint32 sc4[4];
  uint32 bc[3];
  uint32 slot;
};
static_assert(sizeof(SmemT) <= 20 * 1024, "LDS budget for 8 blocks/CU");

__device__ __forceinline__ uint32 kk_of(float p) {
  return (p > 0.01f) ? (__float_as_uint(p) - KBIAS) : 0u;  // 0 = sentinel (-1.0 masked)
}

// suffix-scan 512 bins (2/thread), find pivot bin for `target`; outputs pivot,
// count-strictly-above, pivot-bin count, total; zeroes hist for the next pass.
__device__ __forceinline__ void scan_find(SmemT& sm, uint32 target, int t, int lane, int wv,
                                          uint32& pivot, uint32& cntabove, uint32& pivcnt,
                                          uint32& total) {
  uint32 h0 = sm.hc.hist[2 * t], h1 = sm.hc.hist[2 * t + 1];
  uint32 part = h0 + h1;
  uint32 suf = part;
  for (int off = 1; off < 64; off <<= 1) {
    uint32 v = __shfl_down(suf, off, 64);
    if (lane + off < 64) suf += v;
  }
  if (lane == 0) sm.sc4[wv] = suf;
  __syncthreads();
  uint32 tot = sm.sc4[0] + sm.sc4[1] + sm.sc4[2] + sm.sc4[3];
  uint32 add = 0;
  for (int w = wv + 1; w < 4; ++w) add += sm.sc4[w];
  uint32 mine = suf + add, nxt = mine - part;
  if (mine >= target && nxt < target) {  // unique crossing thread (when target<=tot)
    uint32 acc = nxt + h1;
    if (acc >= target) { sm.bc[0] = 2u * t + 1u; sm.bc[1] = nxt; sm.bc[2] = h1; }
    else               { sm.bc[0] = 2u * t;      sm.bc[1] = acc; sm.bc[2] = h0; }
  }
  __syncthreads();
  sm.hc.hist[2 * t] = 0u;
  sm.hc.hist[2 * t + 1] = 0u;
  pivot = sm.bc[0];
  cntabove = sm.bc[1];
  pivcnt = sm.bc[2];
  total = tot;
  __syncthreads();
}

// ---------------- kernel 1: canonical f64 softmax, single-exp-pass with es[] reuse -------
// Values identical to the r4-validated pipeline: fexp fast path + ambiguity guard +
// libm-exact fallback. es[1..20] kept in registers so each exp is computed ONCE.
// bounds (TPB,5): VGPR cap ~102 comfortably holds the 40-VGPR es1 array (6 pinched).
template <int MODE>
__global__ __launch_bounds__(TPB, 5) void prep_kernel(const float* __restrict__ conf,
                                                      float* __restrict__ probsT,
                                                      double2* __restrict__ ms) {
  __shared__ float tile[TPB * CC];  // 21504 B
  const int blk = blockIdx.x;
  const int b = blockIdx.y;
  const int n0 = blk * TPB;
  const int cnt = (NN - n0 < TPB) ? (NN - n0) : TPB;
  const size_t base = ((size_t)b * NN + n0) * CC;
  if (cnt == TPB) {
    const float4* s4 = (const float4*)(conf + base);  // 16B-aligned (NN%4==0, n0%4==0)
    float4* t4 = (float4*)tile;
    for (int i = threadIdx.x; i < (TPB * CC) / 4; i += TPB) t4[i] = s4[i];
  } else {
    for (int i = threadIdx.x; i < cnt * CC; i += TPB) tile[i] = conf[base + i];
  }
  __syncthreads();
  if (threadIdx.x >= cnt) return;
  const int n = n0 + threadIdx.x;
  const float* cp = tile + threadIdx.x * CC;
  float mx = cp[0];
#pragma unroll
  for (int j = 1; j < CC; ++j) mx = fmaxf(mx, cp[j]);
  const double mxd = (double)mx;

  if (MODE == 0) {
    double es1[CC - 1];                     // exp for classes 1..20 (class 0 only feeds S)
    double S = fexp((double)cp[0] - mxd);   // == 0.0 + e0 of the r4 sum order
#pragma unroll
    for (int j = 1; j < CC; ++j) {
      es1[j - 1] = fexp((double)cp[j] - mxd);
      S += es1[j - 1];
    }
    const double Sinv = 1.0 / S;
    bool slow = false;
    float* op = probsT + (size_t)b * 20 * NN + n;
#pragma unroll
    for (int c2 = 1; c2 < CC; ++c2) {
      double ph = es1[c2 - 1] * Sinv;  // same value as r4's es[c2]*Sinv
      // ambiguity: within 320 f64-ulps of an f32 rounding boundary, or tiny
      uint32 low29 = (uint32)__double_as_longlong(ph) & 0x1FFFFFFFu;
      uint32 dist = (low29 > 0x10000000u) ? (low29 - 0x10000000u) : (0x10000000u - low29);
      slow = slow || (dist <= 320u) || (ph < 1e-30);
      op[(size_t)(c2 - 1) * NN] = (float)ph;
    }
    if (__builtin_expect(slow, 0)) {  // exact spec path (libm exp, sequential sum)
      double es2[CC];
      double S2 = 0.0;
      for (int j = 0; j < CC; ++j) {
        es2[j] = exp((double)cp[j] - mxd);
        S2 += es2[j];
      }
      double Si2 = 1.0 / S2;
      for (int c2 = 1; c2 < CC; ++c2) op[(size_t)(c2 - 1) * NN] = (float)(es2[c2] * Si2);
    }
  } else {
    double S = 0.0;
#pragma unroll
    for (int j = 0; j < CC; ++j) S += exp((double)cp[j] - mxd);
    ms[(size_t)b * NN + n] = make_double2(mxd, 1.0 / S);
  }
}

// per-n prob (MODE 0: exact f32 from probsT; MODE 1/2: libm-exact recompute)
template <int MODE>
__device__ __forceinline__ float prob_one(const float* __restrict__ prow,
                                          const float* __restrict__ conf,
                                          const double2* __restrict__ ms,
                                          int b, int c, int n) {
  if (MODE == 0) {
    return prow[n];
  } else if (MODE == 1) {
    double2 mv = ms[(size_t)b * NN + n];
    float x = conf[((size_t)b * NN + n) * CC + c];
    return (float)(exp((double)x - mv.x) * mv.y);
  } else {
    const float* cp = conf + ((size_t)b * NN + n) * CC;
    float mx = cp[0];
    for (int j = 1; j < CC; ++j) mx = fmaxf(mx, cp[j]);
    double S = 0.0, ec = 0.0;
    for (int j = 0; j < CC; ++j) {
      double e = exp((double)cp[j] - (double)mx);
      S += e;
      if (j == c) ec = e;
    }
    return (float)(ec * (1.0 / S));
  }
}

// one transposed IoU-mask unit: column c, rows [32k, 32k+32) -> u32 word maskT[c*9+k].
// Units exist only for c > 32k. Rows >= c (incl. garbage boxes >= 200 in the k=6
// chunk) are cleared by the trailing triangle mask, so NaN/stale reads are harmless.
// sup = (uni>=0) && (inter > MD*uni): exact 3-way collapse of the r4 compare
// (uni>0 -> f64 cmp; uni==0 -> MD*0=0 so inter>0; uni<0 -> gated off by uni>=0).
__device__ __forceinline__ void mask_unitT(NmsS& nm, int c, int k) {
  const double MD = 0x1.CCCCCDp-2;
  const float xi1 = nm.bx1[c], yi1 = nm.by1[c];
  const float xi2 = nm.bx2[c], yi2 = nm.by2[c];
  const float ai = nm.barea[c];
  const int rbeg = k * 32;
  uint32 w = 0;
#pragma unroll
  for (int r0 = rbeg; r0 < rbeg + 32; r0 += 4) {
    const float4 q1 = *(const float4*)&nm.bx1[r0];
    const float4 q2 = *(const float4*)&nm.by1[r0];
    const float4 q3 = *(const float4*)&nm.bx2[r0];
    const float4 q4 = *(const float4*)&nm.by2[r0];
    const float4 qa = *(const float4*)&nm.barea[r0];
    const float a1[4] = {q1.x, q1.y, q1.z, q1.w};
    const float a2[4] = {q2.x, q2.y, q2.z, q2.w};
    const float a3[4] = {q3.x, q3.y, q3.z, q3.w};
    const float a4[4] = {q4.x, q4.y, q4.z, q4.w};
    const float aa[4] = {qa.x, qa.y, qa.z, qa.w};
#pragma unroll
    for (int e = 0; e < 4; ++e) {
      const int r = r0 + e;
      float xx1 = fmaxf(a1[e], xi1);
      float yy1 = fmaxf(a2[e], yi1);
      float xx2 = fmaxf(a3[e], xi2);
      float yy2 = fmaxf(a4[e], yi2);
      float inter = (xx2 - xx1) * (yy2 - yy1);   // >= 0 (all-max corners, ref quirk)
      float uni = (aa[e] - inter) + ai;          // exact ref op order; may be <= 0
      bool sup = (uni >= 0.0f) && ((double)inter > MD * (double)uni);
      if (sup) w |= 1u << (r & 31);
    }
  }
  const int d = c - rbeg;                 // >= 1 by construction
  if (d < 32) w &= (1u << d) - 1u;        // strict upper triangle: rows r < c only
  nm.maskT[c * 9 + k] = w;
}

// ---------------- kernel 2: per-(b,c) top-k + NMS + output ----------------
template <int MODE>
__global__ __launch_bounds__(TPB, 8) void nms_kernel(
    const float* __restrict__ probsT, const float* __restrict__ conf,
    const double2* __restrict__ ms, const float* __restrict__ loc,
    const float* __restrict__ dbox, float* __restrict__ out) {
  __shared__ SmemT sm;
  const int t = threadIdx.x;
  const int lane = t & 63;
  const int wv = t >> 6;
  const int tb = blockIdx.x;       // XCD-locality swizzle
  const int xcd = tb & 7;
  const int s0i = tb >> 3;
  const int bi = s0i / CC;
  const int c = s0i - bi * CC;
  const int b = bi * 8 + xcd;
  const size_t outbase = (size_t)(b * CC + c) * KK * 5;

  if (c == 0) {  // reference zeroes class 0
    for (int i = t; i < KK * 5; i += TPB) out[outbase + i] = 0.0f;
    return;
  }
  const float* prow = (MODE == 0) ? probsT + ((size_t)b * 20 + (c - 1)) * NN : nullptr;

  sm.hc.hist[t] = 0u;
  sm.hc.hist[t + 256] = 0u;
  if (t == 0) sm.slot = 0u;
  __syncthreads();

  // ---- build 16-bit bucket keys in LDS (ONE global row read) + pass-0 hist ----
  // s16 = (kk>>10)+1 for valid, 0 for sentinel; pass-0 bins = s16>>8 (max 0xD7, spread)
  if (MODE == 0) {
    const float4* p4 = (const float4*)prow;   // NN = 4*2183
    for (int i = t; i < NN / 4; i += TPB) {
      float4 p = p4[i];
      uint32 k0 = kk_of(p.x), k1 = kk_of(p.y), k2 = kk_of(p.z), k3 = kk_of(p.w);
      uint32 s0 = k0 ? (k0 >> 10) + 1u : 0u;
      uint32 s1 = k1 ? (k1 >> 10) + 1u : 0u;
      uint32 s2 = k2 ? (k2 >> 10) + 1u : 0u;
      uint32 s3 = k3 ? (k3 >> 10) + 1u : 0u;
      ((u64*)sm.u.s16)[i] = (u64)s0 | ((u64)s1 << 16) | ((u64)s2 << 32) | ((u64)s3 << 48);
      if (s0) atomicAdd(&sm.hc.hist[s0 >> 8], 1u);
      if (s1) atomicAdd(&sm.hc.hist[s1 >> 8], 1u);
      if (s2) atomicAdd(&sm.hc.hist[s2 >> 8], 1u);
      if (s3) atomicAdd(&sm.hc.hist[s3 >> 8], 1u);
    }
  } else {
    for (int n = t; n < NN; n += TPB) {
      uint32 k = kk_of(prob_one<MODE>(prow, conf, ms, b, c, n));
      uint32 s = k ? (k >> 10) + 1u : 0u;
      sm.u.s16[n] = (u16)s;
      if (s) atomicAdd(&sm.hc.hist[s >> 8], 1u);
    }
  }
  __syncthreads();
  uint32 P0, cg0, pc0, total;
  scan_find(sm, (uint32)KK, t, lane, wv, P0, cg0, pc0, total);

  const bool few = total < (uint32)KK;
  uint32 P16, cgA = 0, eqc = 0, ncand;
  if (!few) {
    // ---- pass 1: bins = s16 & 0xFF within high-byte P0 (LDS scan, no global) ----
    for (int i = t; i < NN / 2; i += TPB) {
      uint32 w = ((const uint32*)sm.u.s16)[i];
      uint32 a = w & 0xFFFFu, bq = w >> 16;
      if ((a >> 8) == P0) atomicAdd(&sm.hc.hist[a & 0xFFu], 1u);
      if ((bq >> 8) == P0) atomicAdd(&sm.hc.hist[bq & 0xFFu], 1u);
    }
    __syncthreads();
    uint32 P1, cg1, pc1, tot1;
    scan_find(sm, (uint32)KK - cg0, t, lane, wv, P1, cg1, pc1, tot1);
    P16 = (P0 << 8) | P1;
    cgA = cg0 + cg1;
    eqc = pc1;
    ncand = cgA + eqc;   // count with s16 >= P16 (superset of top-200)
  } else {
    P16 = 1u;            // all valid boxes are candidates
    ncand = total;
  }

  u64 val = 0;
  if (ncand <= 256u) {
    // ---- fast path: collect candidate indices, gather exact probs, sort exactly ----
    sm.hc.cand[t] = 0ull;
    __syncthreads();
    for (int i = t; i < NN / 2; i += TPB) {
      uint32 w = ((const uint32*)sm.u.s16)[i];
      uint32 a = w & 0xFFFFu, bq = w >> 16;
      if (a >= P16) { uint32 s = atomicAdd(&sm.slot, 1u); sm.hc.cand[s] = (u64)(2 * i); }
      if (bq >= P16) { uint32 s = atomicAdd(&sm.slot, 1u); sm.hc.cand[s] = (u64)(2 * i + 1); }
    }
    __syncthreads();
    if (few) {
      // pad with the lowest-index (200-total) masked boxes (equal -1.0 ties by index)
      const int base = t * CH;
      const int endn = (base + CH < NN) ? (base + CH) : NN;
      uint32 cz = 0;
      for (int n = base; n < endn; ++n) cz += (sm.u.s16[n] == 0);
      uint32 incl = cz;
      for (int off = 1; off < 64; off <<= 1) {
        uint32 v = __shfl_up(incl, off, 64);
        if (lane >= off) incl += v;
      }
      if (lane == 63) sm.sc4[wv] = incl;
      __syncthreads();
      uint32 add = 0;
      for (int w2 = 0; w2 < wv; ++w2) add += sm.sc4[w2];
      uint32 g = add + incl - cz;
      const uint32 npad = (uint32)KK - ncand;
      if (cz && g < npad) {
        for (int n = base; n < endn && g < npad; ++n)
          if (sm.u.s16[n] == 0) { sm.hc.cand[ncand + g] = (u64)n; ++g; }
      }
      __syncthreads();
    }
    const uint32 ntot = few ? (uint32)KK : ncand;   // >= 200 always
    if (t < (int)ntot) {
      uint32 idx = (uint32)sm.hc.cand[t];
      uint32 k = (t < (int)ncand) ? kk_of(prob_one<MODE>(prow, conf, ms, b, c, (int)idx)) : 0u;
      val = ((u64)k << 32) | (uint32)(~idx);
    }
  } else {
    // ---- rare exact fallback: refine low 10 bits of kk within bucket P16-1 ----
    const uint32 BK = P16 - 1u;
    const uint32 tgt = (uint32)KK - cgA;
    for (int n = t; n < NN; n += TPB) {
      uint32 k = kk_of(prob_one<MODE>(prow, conf, ms, b, c, n));
      if (k && (k >> 10) == BK) atomicAdd(&sm.hc.hist[(k >> 5) & 31u], 1u);
    }
    __syncthreads();
    uint32 q0, d0, px, tx;
    scan_find(sm, tgt, t, lane, wv, q0, d0, px, tx);
    for (int n = t; n < NN; n += TPB) {
      uint32 k = kk_of(prob_one<MODE>(prow, conf, ms, b, c, n));
      if (k && (k >> 5) == ((BK << 5) | q0)) atomicAdd(&sm.hc.hist[k & 31u], 1u);
    }
    __syncthreads();
    uint32 q1, d1, py, ty;
    scan_find(sm, tgt - d0, t, lane, wv, q1, d1, py, ty);
    const uint32 T = (BK << 10) | (q0 << 5) | q1;
    const uint32 cnt_gt = cgA + d0 + d1;
    const uint32 m_need = (uint32)KK - cnt_gt;
    sm.hc.cand[t] = 0ull;           // hist fully dead from here on
    if (t == 0) sm.slot = 0u;
    __syncthreads();
    const int base = t * CH;
    const int endn = (base + CH < NN) ? (base + CH) : NN;
    uint32 cnteq = 0;
    for (int n = base; n < endn; ++n) {
      uint32 k = kk_of(prob_one<MODE>(prow, conf, ms, b, c, n));
      if (k > T) {
        uint32 s = atomicAdd(&sm.slot, 1u);
        sm.hc.cand[s] = ((u64)k << 32) | (uint32)(~(uint32)n);
      }
      cnteq += (k == T);
    }
    uint32 incl = cnteq;
    for (int off = 1; off < 64; off <<= 1) {
      uint32 v = __shfl_up(incl, off, 64);
      if (lane >= off) incl += v;
    }
    if (lane == 63) sm.sc4[wv] = incl;
    __syncthreads();
    uint32 add = 0;
    for (int w2 = 0; w2 < wv; ++w2) add += sm.sc4[w2];
    uint32 g = add + incl - cnteq;
    if (cnteq && g < m_need) {
      for (int n = base; n < endn && g < m_need; ++n) {
        uint32 k = kk_of(prob_one<MODE>(prow, conf, ms, b, c, n));
        if (k == T) {
          sm.hc.cand[cnt_gt + g] = ((u64)T << 32) | (uint32)(~(uint32)n);
          ++g;
        }
      }
    }
    __syncthreads();
    val = sm.hc.cand[t];
  }

  // ---- bitonic sort 256 in registers (key desc, idx asc) ----
  for (int kk = 2; kk <= 256; kk <<= 1) {
    for (int j = kk >> 1; j > 0; j >>= 1) {
      u64 other;
      if (j >= 64) {
        __syncthreads();
        sm.hc.cand[t] = val;
        __syncthreads();
        other = sm.hc.cand[t ^ j];
      } else {
        other = __shfl_xor((unsigned long long)val, j, 64);
      }
      const bool takeMax = ((t & kk) == 0) == ((t & j) == 0);
      val = takeMax ? (val > other ? val : other) : (val < other ? val : other);
    }
  }
  __syncthreads();  // s16/nms union: drain last select-phase reads before decode writes

  // ---- gather + decode (exact reference fp32 op order; guarded fexp) ----
  // all threads also zero maskT here (below-diagonal words must be 0 for the walk)
  {
    uint32* mz = sm.u.nms.maskT + t * 9;
#pragma unroll
    for (int q = 0; q < 9; ++q) mz[q] = 0u;
  }
  if (t < KK) {
    uint32 k32 = (uint32)(val >> 32);
    uint32 idx = ~((uint32)val);
    bool valid = k32 != 0u;
    float score = valid ? __uint_as_float(k32 + KBIAS) : -1.0f;
    const float4 lc = ((const float4*)loc)[(size_t)b * NN + idx];
    const float4 db = ((const float4*)dbox)[idx];
    float cx = db.x + (lc.x * 0.1f) * db.z;
    float cy = db.y + (lc.y * 0.1f) * db.w;
    float w_ = db.z * exp_f32_exact(lc.z * 0.2f);
    float h_ = db.w * exp_f32_exact(lc.w * 0.2f);
    float x1 = cx - w_ * 0.5f;
    float y1 = cy - h_ * 0.5f;
    float x2 = x1 + w_;
    float y2 = y1 + h_;
    sm.u.nms.bx1[t] = x1;
    sm.u.nms.by1[t] = y1;
    sm.u.nms.bx2[t] = x2;
    sm.u.nms.by2[t] = y2;
    sm.u.nms.barea[t] = (x2 - x1) * (y2 - y1);
    sm.u.nms.bscore[t] = score;
  } else {
    sm.u.nms.bscore[t] = -1.0f;
  }
  __syncthreads();

  // ---- transposed IoU mask: 721 uniform 32-row units over all threads ----
  // unit u -> (col c, row-chunk k): k-ranges [0,199) [199,366) [366,501) [501,604)
  // [604,675) [675,714) [714,721). Round 3 goes to HIGH threads so wave 0 (the
  // walker) carries the lighter mask load.
  {
    auto do_unit = [&](int u) {
      int cq, k;
      if (u < 199)      { k = 0; cq = u + 1; }
      else if (u < 366) { k = 1; cq = u - 166; }
      else if (u < 501) { k = 2; cq = u - 301; }
      else if (u < 604) { k = 3; cq = u - 404; }
      else if (u < 675) { k = 4; cq = u - 475; }
      else if (u < 714) { k = 5; cq = u - 514; }
      else              { k = 6; cq = u - 521; }
      mask_unitT(sm.u.nms, cq, k);
    };
    do_unit(t);
    do_unit(256 + t);
    if (t >= 47) do_unit(512 + (255 - t));   // u in [512,720]
  }
  __syncthreads();

  // ---- greedy walk on wave 0: register-resident columns + ballot-maintained ----
  // suppressed word. Lane j owns cols {j,64+j,128+j,192+j} as a 1-bit flag each;
  // per 64-block it loads 2 u32 column-words/col (8 ds_read_b32, 2-way alias).
  // Suppressed steps are pure SALU (test+branch); kept steps are 4 bfe+or + ballot.
  if (wv == 0) {
    uint32 sf0 = (sm.u.nms.bscore[lane] > 0.01f) ? 0u : 1u;
    uint32 sf1 = (sm.u.nms.bscore[64 + lane] > 0.01f) ? 0u : 1u;
    uint32 sf2 = (sm.u.nms.bscore[128 + lane] > 0.01f) ? 0u : 1u;
    uint32 sf3 = (lane >= 8) ? 1u : ((sm.u.nms.bscore[192 + lane] > 0.01f) ? 0u : 1u);
    const uint32* MT = sm.u.nms.maskT;
    const int l0 = lane * 9, l1 = (64 + lane) * 9, l2 = (128 + lane) * 9, l3 = (192 + lane) * 9;
    u64 kept0, kept1, kept2, kept3;

#define WBLK(W, CNT, KOUT, SF)                                                 \
  {                                                                            \
    uint32 a0 = MT[l0 + 2 * W], b0 = MT[l0 + 2 * W + 1];                       \
    uint32 a1 = MT[l1 + 2 * W], b1 = MT[l1 + 2 * W + 1];                       \
    uint32 a2 = MT[l2 + 2 * W], b2 = MT[l2 + 2 * W + 1];                       \
    uint32 a3 = MT[l3 + 2 * W], b3 = MT[l3 + 2 * W + 1];                       \
    u64 S = __ballot(SF != 0u);                                                \
    u64 kw = 0;                                                                \
    _Pragma("unroll")                                                          \
    for (int ii = 0; ii < (CNT); ++ii) {                                       \
      if (!((S >> ii) & 1ull)) {                                               \
        kw |= 1ull << ii;                                                      \
        sf0 |= (ii < 32) ? ((a0 >> ii) & 1u) : ((b0 >> (ii - 32)) & 1u);       \
        sf1 |= (ii < 32) ? ((a1 >> ii) & 1u) : ((b1 >> (ii - 32)) & 1u);       \
        sf2 |= (ii < 32) ? ((a2 >> ii) & 1u) : ((b2 >> (ii - 32)) & 1u);       \
        sf3 |= (ii < 32) ? ((a3 >> ii) & 1u) : ((b3 >> (ii - 32)) & 1u);       \
        S = __ballot(SF != 0u);                                                \
      }                                                                        \
    }                                                                          \
    KOUT = kw;                                                                 \
  }
    WBLK(0, 64, kept0, sf0)
    WBLK(1, 64, kept1, sf1)
    WBLK(2, 64, kept2, sf2)
    WBLK(3, 8, kept3, sf3)
#undef WBLK
    if (lane == 0) {
      sm.u.nms.kept[0] = kept0; sm.u.nms.kept[1] = kept1;
      sm.u.nms.kept[2] = kept2; sm.u.nms.kept[3] = kept3;
    }
  } else {
    // waves 1-3: zero the whole (b,c) output slab in the walk's shadow
    float4 z4 = make_float4(0.f, 0.f, 0.f, 0.f);
    float4* o4 = (float4*)(out + outbase);          // 1000 floats = 250 float4
    for (int i = t - 64; i < (KK * 5) / 4; i += 192) o4[i] = z4;
  }
  __syncthreads();

  // ---- compacted output (kept rows only; rest pre-zeroed) ----
  if (t < KK) {
    const u64 K0 = sm.u.nms.kept[0], K1 = sm.u.nms.kept[1];
    const u64 K2 = sm.u.nms.kept[2], K3 = sm.u.nms.kept[3];
    const int w = t >> 6;
    const int bit = t & 63;
    u64 kw = (w == 0) ? K0 : (w == 1) ? K1 : (w == 2) ? K2 : K3;
    bool kp = (kw >> bit) & 1ull;
    if (kp) {
      u64 lowm = (bit == 0) ? 0ull : (~0ull >> (64 - bit));
      int d = __popcll(kw & lowm);
      if (w > 0) d += __popcll(K0);
      if (w > 1) d += __popcll(K1);
      if (w > 2) d += __popcll(K2);
      float* o = out + outbase + (size_t)d * 5;
      o[0] = sm.u.nms.bscore[t];
      o[1] = sm.u.nms.bx1[t];
      o[2] = sm.u.nms.by1[t];
      o[3] = sm.u.nms.bx2[t];
      o[4] = sm.u.nms.by2[t];
    }
  }
}

// ---------------- launch ----------------
extern "C" void kernel_launch(void* const* d_in, const int* in_sizes, int n_in,
                              void* d_out, int out_size, void* d_ws, size_t ws_size,
                              hipStream_t stream) {
  (void)in_sizes; (void)n_in; (void)out_size;
  const float* loc = (const float*)d_in[0];
  const float* conf = (const float*)d_in[1];
  const float* dbox = (const float*)d_in[2];
  float* out = (float*)d_out;

  const size_t needA = (size_t)BB * 20 * NN * sizeof(float);  // 178.8 MB transposed probs
  const size_t needB = (size_t)BB * NN * sizeof(double2);     // 35.8 MB {max, 1/S}
  dim3 blk(TPB);
  dim3 g1((NN + TPB - 1) / TPB, BB);
  const int g2 = BB * CC;

  if (ws_size >= needA) {
    float* probsT = (float*)d_ws;
    prep_kernel<0><<<g1, blk, 0, stream>>>(conf, probsT, nullptr);
    nms_kernel<0><<<g2, blk, 0, stream>>>(probsT, conf, nullptr, loc, dbox, out);
  } else if (ws_size >= needB) {
    double2* msp = (double2*)d_ws;
    prep_kernel<1><<<g1, blk, 0, stream>>>(conf, nullptr, msp);
    nms_kernel<1><<<g2, blk, 0, stream>>>(nullptr, conf, msp, loc, dbox, out);
  } else {
    nms_kernel<2><<<g2, blk, 0, stream>>>(nullptr, conf, nullptr, loc, dbox, out);
  }
}

// Round 6
// 437.880 us; speedup vs baseline: 1.2588x; 1.2588x over previous
//
#include <hip/hip_runtime.h>
#include <cstdint>

#pragma clang fp contract(off)

#define TPB 256
typedef unsigned int uint32;
typedef unsigned short u16;
typedef unsigned long long u64;

constexpr int BB = 256;    // batch
constexpr int NN = 8732;   // boxes
constexpr int CC = 21;     // classes
constexpr int KK = 200;    // top-k
constexpr int CH = (NN + TPB - 1) / TPB;   // 35 contiguous elems per thread (index order)
constexpr uint32 KBIAS = 0x3C23D70Au;      // bits(0.01f); kk = bits(p)-KBIAS in [1, 0x35C28F6]

// ---------------- fast f64 exp (fast path only; guarded by interval check) ----------------
__device__ __forceinline__ double fexp(double a) {
  const double L2E = 1.4426950408889634074;
  const double SHIFT = 6755399441055744.0;  // 1.5*2^52
  double t = __builtin_fma(a, L2E, SHIFT);
  int i = (int)__double_as_longlong(t);
  double n = t - SHIFT;
  double r = __builtin_fma(n, -6.93147180369123816490e-01, a);
  r = __builtin_fma(n, -1.90821492927058770002e-10, r);
  double p = 1.6059043836821614599e-10;
  p = __builtin_fma(p, r, 2.0876756987868098979e-9);
  p = __builtin_fma(p, r, 2.5052108385441718775e-8);
  p = __builtin_fma(p, r, 2.7557319223985890653e-7);
  p = __builtin_fma(p, r, 2.7557319223985890653e-6);
  p = __builtin_fma(p, r, 2.4801587301587301587e-5);
  p = __builtin_fma(p, r, 1.9841269841269841270e-4);
  p = __builtin_fma(p, r, 1.3888888888888888889e-3);
  p = __builtin_fma(p, r, 8.3333333333333333333e-3);
  p = __builtin_fma(p, r, 4.1666666666666666667e-2);
  p = __builtin_fma(p, r, 1.6666666666666666667e-1);
  p = __builtin_fma(p, r, 0.5);
  p = __builtin_fma(p, r, 1.0);
  p = __builtin_fma(p, r, 1.0);
  return p * __longlong_as_double((long long)(1023 + i) << 52);
}

// f32(exp(x)) via fexp with libm fallback when the f64 result sits within 65536
// f64-ulps of an f32 rounding boundary (fexp vs libm differ by << that margin).
__device__ __forceinline__ float exp_f32_exact(float xf) {
  double v = fexp((double)xf);
  uint32 low29 = (uint32)__double_as_longlong(v) & 0x1FFFFFFFu;
  uint32 dist = (low29 > 0x10000000u) ? (low29 - 0x10000000u) : (0x10000000u - low29);
  if (__builtin_expect(dist <= 65536u, 0)) v = exp((double)xf);
  return (float)v;
}

__device__ __forceinline__ u64 rfl64(u64 v) {
  uint32 lo = (uint32)__builtin_amdgcn_readfirstlane((int)(uint32)v);
  uint32 hi = (uint32)__builtin_amdgcn_readfirstlane((int)(uint32)(v >> 32));
  return ((u64)hi << 32) | lo;
}

// ---------------- shared memory ----------------
struct NmsS {
  alignas(16) float bx1[256];
  alignas(16) float by1[256];
  alignas(16) float bx2[256];
  alignas(16) float by2[256];
  alignas(16) float barea[256];
  alignas(16) float bscore[256];
  alignas(16) u64 mask[KK][4];
  u64 kept[4];
};
struct SmemT {
  union alignas(16) UU {
    u16 s16[NN];   // 17464 B (select phase; 16-bit bucket keys)
    NmsS nms;      // 12576 B (NMS phase)
  } u;
  // hist's liveness (incl. rare-fallback refinement scans) ends before the first
  // cand write in every path -> safe union; saves 2 KB -> 8 blocks/CU.
  union alignas(16) HC {
    uint32 hist[512];
    u64 cand[256];
  } hc;
  uint32 sc4[4];
  uint32 bc[3];
  uint32 slot;
};
static_assert(sizeof(SmemT) <= 20 * 1024, "LDS budget for 8 blocks/CU");

__device__ __forceinline__ uint32 kk_of(float p) {
  return (p > 0.01f) ? (__float_as_uint(p) - KBIAS) : 0u;  // 0 = sentinel (-1.0 masked)
}

// suffix-scan 512 bins (2/thread), find pivot bin for `target`; outputs pivot,
// count-strictly-above, pivot-bin count, total; zeroes hist for the next pass.
__device__ __forceinline__ void scan_find(SmemT& sm, uint32 target, int t, int lane, int wv,
                                          uint32& pivot, uint32& cntabove, uint32& pivcnt,
                                          uint32& total) {
  uint32 h0 = sm.hc.hist[2 * t], h1 = sm.hc.hist[2 * t + 1];
  uint32 part = h0 + h1;
  uint32 suf = part;
  for (int off = 1; off < 64; off <<= 1) {
    uint32 v = __shfl_down(suf, off, 64);
    if (lane + off < 64) suf += v;
  }
  if (lane == 0) sm.sc4[wv] = suf;
  __syncthreads();
  uint32 tot = sm.sc4[0] + sm.sc4[1] + sm.sc4[2] + sm.sc4[3];
  uint32 add = 0;
  for (int w = wv + 1; w < 4; ++w) add += sm.sc4[w];
  uint32 mine = suf + add, nxt = mine - part;
  if (mine >= target && nxt < target) {  // unique crossing thread (when target<=tot)
    uint32 acc = nxt + h1;
    if (acc >= target) { sm.bc[0] = 2u * t + 1u; sm.bc[1] = nxt; sm.bc[2] = h1; }
    else               { sm.bc[0] = 2u * t;      sm.bc[1] = acc; sm.bc[2] = h0; }
  }
  __syncthreads();
  sm.hc.hist[2 * t] = 0u;
  sm.hc.hist[2 * t + 1] = 0u;
  pivot = sm.bc[0];
  cntabove = sm.bc[1];
  pivcnt = sm.bc[2];
  total = tot;
  __syncthreads();
}

// ---------------- kernel 1: canonical f64 softmax, single-exp-pass with es[] reuse -------
// Values identical to the r4-validated pipeline: fexp fast path + ambiguity guard +
// libm-exact fallback. es[1..20] kept in registers so each exp is computed ONCE.
// bounds (TPB,5): VGPR cap ~102 comfortably holds the 40-VGPR es1 array.
template <int MODE>
__global__ __launch_bounds__(TPB, 5) void prep_kernel(const float* __restrict__ conf,
                                                      float* __restrict__ probsT,
                                                      double2* __restrict__ ms) {
  __shared__ float tile[TPB * CC];  // 21504 B
  const int blk = blockIdx.x;
  const int b = blockIdx.y;
  const int n0 = blk * TPB;
  const int cnt = (NN - n0 < TPB) ? (NN - n0) : TPB;
  const size_t base = ((size_t)b * NN + n0) * CC;
  if (cnt == TPB) {
    const float4* s4 = (const float4*)(conf + base);  // 16B-aligned (NN%4==0, n0%4==0)
    float4* t4 = (float4*)tile;
    for (int i = threadIdx.x; i < (TPB * CC) / 4; i += TPB) t4[i] = s4[i];
  } else {
    for (int i = threadIdx.x; i < cnt * CC; i += TPB) tile[i] = conf[base + i];
  }
  __syncthreads();
  if (threadIdx.x >= cnt) return;
  const int n = n0 + threadIdx.x;
  const float* cp = tile + threadIdx.x * CC;
  float mx = cp[0];
#pragma unroll
  for (int j = 1; j < CC; ++j) mx = fmaxf(mx, cp[j]);
  const double mxd = (double)mx;

  if (MODE == 0) {
    double es1[CC - 1];                     // exp for classes 1..20 (class 0 only feeds S)
    double S = fexp((double)cp[0] - mxd);   // == 0.0 + e0 of the r4 sum order
#pragma unroll
    for (int j = 1; j < CC; ++j) {
      es1[j - 1] = fexp((double)cp[j] - mxd);
      S += es1[j - 1];
    }
    const double Sinv = 1.0 / S;
    bool slow = false;
    float* op = probsT + (size_t)b * 20 * NN + n;
#pragma unroll
    for (int c2 = 1; c2 < CC; ++c2) {
      double ph = es1[c2 - 1] * Sinv;  // same value as r4's es[c2]*Sinv
      // ambiguity: within 320 f64-ulps of an f32 rounding boundary, or tiny
      uint32 low29 = (uint32)__double_as_longlong(ph) & 0x1FFFFFFFu;
      uint32 dist = (low29 > 0x10000000u) ? (low29 - 0x10000000u) : (0x10000000u - low29);
      slow = slow || (dist <= 320u) || (ph < 1e-30);
      op[(size_t)(c2 - 1) * NN] = (float)ph;
    }
    if (__builtin_expect(slow, 0)) {  // exact spec path (libm exp, sequential sum)
      double es2[CC];
      double S2 = 0.0;
      for (int j = 0; j < CC; ++j) {
        es2[j] = exp((double)cp[j] - mxd);
        S2 += es2[j];
      }
      double Si2 = 1.0 / S2;
      for (int c2 = 1; c2 < CC; ++c2) op[(size_t)(c2 - 1) * NN] = (float)(es2[c2] * Si2);
    }
  } else {
    double S = 0.0;
#pragma unroll
    for (int j = 0; j < CC; ++j) S += exp((double)cp[j] - mxd);
    ms[(size_t)b * NN + n] = make_double2(mxd, 1.0 / S);
  }
}

// per-n prob (MODE 0: exact f32 from probsT; MODE 1/2: libm-exact recompute)
template <int MODE>
__device__ __forceinline__ float prob_one(const float* __restrict__ prow,
                                          const float* __restrict__ conf,
                                          const double2* __restrict__ ms,
                                          int b, int c, int n) {
  if (MODE == 0) {
    return prow[n];
  } else if (MODE == 1) {
    double2 mv = ms[(size_t)b * NN + n];
    float x = conf[((size_t)b * NN + n) * CC + c];
    return (float)(exp((double)x - mv.x) * mv.y);
  } else {
    const float* cp = conf + ((size_t)b * NN + n) * CC;
    float mx = cp[0];
    for (int j = 1; j < CC; ++j) mx = fmaxf(mx, cp[j]);
    double S = 0.0, ec = 0.0;
    for (int j = 0; j < CC; ++j) {
      double e = exp((double)cp[j] - (double)mx);
      S += e;
      if (j == c) ec = e;
    }
    return (float)(ec * (1.0 / S));
  }
}

// exact replacement for (double)inter > MD*(double)uni:
// MDf = 0x1.CCCCCDp-2f has a 24-bit mantissa, so MDf*uni is exact in f64 and equals
// pq + er with pq = f32 product and er = fmaf residual (exact 2-prod; products are
// >= ~1e-16 here, far from subnormal territory). |er| <= ulp(pq)/2, so:
//   inter > pq            -> inter >= pq+ulp > pq+er -> true
//   inter < pq            -> inter <= pq-ulp < pq+er -> false
//   inter == pq           -> answer is (er < 0)
__device__ __forceinline__ bool iou_gt(float inter, float uni) {
  const float MDf = 0x1.CCCCCDp-2f;
  float pq = MDf * uni;
  float er = __builtin_fmaf(MDf, uni, -pq);
  return (inter > pq) | ((inter == pq) & (er < 0.0f));
}

// one 32-column IoU-mask unit: row r's bits for cols [32c, 32c+32).
// Units exist only for r < 32(c+1); unwritten below-diagonal words are never
// consumed by the walk (their columns are always already-passed at step r).
// sup = (uni>=0) && iou_gt(inter,uni): exact 3-way collapse of the r4 compare
// (uni>0 -> f64 cmp; uni==0 -> MD*0=0 so inter>0; uni<0 -> gated off by uni>=0).
// Triangle (j>r) applied once per unit as a trailing mask.
__device__ __forceinline__ void mask_unit32(NmsS& nm, int r, int c) {
  const float xi1 = nm.bx1[r], yi1 = nm.by1[r];
  const float xi2 = nm.bx2[r], yi2 = nm.by2[r];
  const float ai = nm.barea[r];
  const int jbeg = c * 32;
  uint32 w = 0;
#pragma unroll
  for (int j0 = jbeg; j0 < jbeg + 32; j0 += 4) {   // lane-uniform j0 pattern
    const float4 q1 = *(const float4*)&nm.bx1[j0];
    const float4 q2 = *(const float4*)&nm.by1[j0];
    const float4 q3 = *(const float4*)&nm.bx2[j0];
    const float4 q4 = *(const float4*)&nm.by2[j0];
    const float4 qa = *(const float4*)&nm.barea[j0];
    const float a1[4] = {q1.x, q1.y, q1.z, q1.w};
    const float a2[4] = {q2.x, q2.y, q2.z, q2.w};
    const float a3[4] = {q3.x, q3.y, q3.z, q3.w};
    const float a4[4] = {q4.x, q4.y, q4.z, q4.w};
    const float aa[4] = {qa.x, qa.y, qa.z, qa.w};
#pragma unroll
    for (int e = 0; e < 4; ++e) {
      const int j = j0 + e;
      float xx1 = fmaxf(a1[e], xi1);
      float yy1 = fmaxf(a2[e], yi1);
      float xx2 = fmaxf(a3[e], xi2);
      float yy2 = fmaxf(a4[e], yi2);
      float inter = (xx2 - xx1) * (yy2 - yy1);   // >= 0 (all-max corners, ref quirk)
      float uni = (aa[e] - inter) + ai;          // exact ref op order; may be <= 0
      bool sup = (uni >= 0.0f) && iou_gt(inter, uni);
      if (sup) w |= 1u << (j & 31);
    }
  }
  const int d = r - jbeg;
  if (d >= 0) w &= (0xFFFFFFFEu << d);   // diagonal chunk: clear bits j<=r
  ((uint32*)&nm.mask[r][0])[c] = w;
}

// short unit: cols 192..199 -> uint32 word [6] (bits 8..31 zero). Word [7] stays
// garbage: its columns (>=224) are pre-suppressed in the walk and never kept.
__device__ __forceinline__ void mask_unit_short(NmsS& nm, int r) {
  const float xi1 = nm.bx1[r], yi1 = nm.by1[r];
  const float xi2 = nm.bx2[r], yi2 = nm.by2[r];
  const float ai = nm.barea[r];
  uint32 w = 0;
#pragma unroll
  for (int j0 = 192; j0 < 200; j0 += 4) {
    const float4 q1 = *(const float4*)&nm.bx1[j0];
    const float4 q2 = *(const float4*)&nm.by1[j0];
    const float4 q3 = *(const float4*)&nm.bx2[j0];
    const float4 q4 = *(const float4*)&nm.by2[j0];
    const float4 qa = *(const float4*)&nm.barea[j0];
    const float a1[4] = {q1.x, q1.y, q1.z, q1.w};
    const float a2[4] = {q2.x, q2.y, q2.z, q2.w};
    const float a3[4] = {q3.x, q3.y, q3.z, q3.w};
    const float a4[4] = {q4.x, q4.y, q4.z, q4.w};
    const float aa[4] = {qa.x, qa.y, qa.z, qa.w};
#pragma unroll
    for (int e = 0; e < 4; ++e) {
      const int j = j0 + e;
      float xx1 = fmaxf(a1[e], xi1);
      float yy1 = fmaxf(a2[e], yi1);
      float xx2 = fmaxf(a3[e], xi2);
      float yy2 = fmaxf(a4[e], yi2);
      float inter = (xx2 - xx1) * (yy2 - yy1);
      float uni = (aa[e] - inter) + ai;
      bool sup = (uni >= 0.0f) && iou_gt(inter, uni);
      if (sup) w |= 1u << (j & 31);
    }
  }
  const int d = r - 192;
  if (d >= 0) w &= (0xFFFFFFFEu << d);
  ((uint32*)&nm.mask[r][0])[6] = w;
}

// ---------------- kernel 2: per-(b,c) top-k + NMS + output ----------------
template <int MODE>
__global__ __launch_bounds__(TPB, 8) void nms_kernel(
    const float* __restrict__ probsT, const float* __restrict__ conf,
    const double2* __restrict__ ms, const float* __restrict__ loc,
    const float* __restrict__ dbox, float* __restrict__ out) {
  __shared__ SmemT sm;
  const int t = threadIdx.x;
  const int lane = t & 63;
  const int wv = t >> 6;
  const int tb = blockIdx.x;       // XCD-locality swizzle
  const int xcd = tb & 7;
  const int s0i = tb >> 3;
  const int bi = s0i / CC;
  const int c = s0i - bi * CC;
  const int b = bi * 8 + xcd;
  const size_t outbase = (size_t)(b * CC + c) * KK * 5;

  if (c == 0) {  // reference zeroes class 0
    for (int i = t; i < KK * 5; i += TPB) out[outbase + i] = 0.0f;
    return;
  }
  const float* prow = (MODE == 0) ? probsT + ((size_t)b * 20 + (c - 1)) * NN : nullptr;

  sm.hc.hist[t] = 0u;
  sm.hc.hist[t + 256] = 0u;
  if (t == 0) sm.slot = 0u;
  __syncthreads();

  // ---- build 16-bit bucket keys in LDS (ONE global row read) + pass-0 hist ----
  // s16 = (kk>>10)+1 for valid, 0 for sentinel; pass-0 bins = s16>>8 (max 0xD7, spread)
  if (MODE == 0) {
    const float4* p4 = (const float4*)prow;   // NN = 4*2183
    for (int i = t; i < NN / 4; i += TPB) {
      float4 p = p4[i];
      uint32 k0 = kk_of(p.x), k1 = kk_of(p.y), k2 = kk_of(p.z), k3 = kk_of(p.w);
      uint32 s0 = k0 ? (k0 >> 10) + 1u : 0u;
      uint32 s1 = k1 ? (k1 >> 10) + 1u : 0u;
      uint32 s2 = k2 ? (k2 >> 10) + 1u : 0u;
      uint32 s3 = k3 ? (k3 >> 10) + 1u : 0u;
      ((u64*)sm.u.s16)[i] = (u64)s0 | ((u64)s1 << 16) | ((u64)s2 << 32) | ((u64)s3 << 48);
      if (s0) atomicAdd(&sm.hc.hist[s0 >> 8], 1u);
      if (s1) atomicAdd(&sm.hc.hist[s1 >> 8], 1u);
      if (s2) atomicAdd(&sm.hc.hist[s2 >> 8], 1u);
      if (s3) atomicAdd(&sm.hc.hist[s3 >> 8], 1u);
    }
  } else {
    for (int n = t; n < NN; n += TPB) {
      uint32 k = kk_of(prob_one<MODE>(prow, conf, ms, b, c, n));
      uint32 s = k ? (k >> 10) + 1u : 0u;
      sm.u.s16[n] = (u16)s;
      if (s) atomicAdd(&sm.hc.hist[s >> 8], 1u);
    }
  }
  __syncthreads();
  uint32 P0, cg0, pc0, total;
  scan_find(sm, (uint32)KK, t, lane, wv, P0, cg0, pc0, total);

  const bool few = total < (uint32)KK;
  uint32 P16, cgA = 0, eqc = 0, ncand;
  if (!few) {
    // ---- pass 1: bins = s16 & 0xFF within high-byte P0 (LDS scan, no global) ----
    for (int i = t; i < NN / 2; i += TPB) {
      uint32 w = ((const uint32*)sm.u.s16)[i];
      uint32 a = w & 0xFFFFu, bq = w >> 16;
      if ((a >> 8) == P0) atomicAdd(&sm.hc.hist[a & 0xFFu], 1u);
      if ((bq >> 8) == P0) atomicAdd(&sm.hc.hist[bq & 0xFFu], 1u);
    }
    __syncthreads();
    uint32 P1, cg1, pc1, tot1;
    scan_find(sm, (uint32)KK - cg0, t, lane, wv, P1, cg1, pc1, tot1);
    P16 = (P0 << 8) | P1;
    cgA = cg0 + cg1;
    eqc = pc1;
    ncand = cgA + eqc;   // count with s16 >= P16 (superset of top-200)
  } else {
    P16 = 1u;            // all valid boxes are candidates
    ncand = total;
  }

  u64 val = 0;
  if (ncand <= 256u) {
    // ---- fast path: collect candidate indices, gather exact probs, sort exactly ----
    sm.hc.cand[t] = 0ull;
    __syncthreads();
    for (int i = t; i < NN / 2; i += TPB) {
      uint32 w = ((const uint32*)sm.u.s16)[i];
      uint32 a = w & 0xFFFFu, bq = w >> 16;
      if (a >= P16) { uint32 s = atomicAdd(&sm.slot, 1u); sm.hc.cand[s] = (u64)(2 * i); }
      if (bq >= P16) { uint32 s = atomicAdd(&sm.slot, 1u); sm.hc.cand[s] = (u64)(2 * i + 1); }
    }
    __syncthreads();
    if (few) {
      // pad with the lowest-index (200-total) masked boxes (equal -1.0 ties by index)
      const int base = t * CH;
      const int endn = (base + CH < NN) ? (base + CH) : NN;
      uint32 cz = 0;
      for (int n = base; n < endn; ++n) cz += (sm.u.s16[n] == 0);
      uint32 incl = cz;
      for (int off = 1; off < 64; off <<= 1) {
        uint32 v = __shfl_up(incl, off, 64);
        if (lane >= off) incl += v;
      }
      if (lane == 63) sm.sc4[wv] = incl;
      __syncthreads();
      uint32 add = 0;
      for (int w2 = 0; w2 < wv; ++w2) add += sm.sc4[w2];
      uint32 g = add + incl - cz;
      const uint32 npad = (uint32)KK - ncand;
      if (cz && g < npad) {
        for (int n = base; n < endn && g < npad; ++n)
          if (sm.u.s16[n] == 0) { sm.hc.cand[ncand + g] = (u64)n; ++g; }
      }
      __syncthreads();
    }
    const uint32 ntot = few ? (uint32)KK : ncand;   // >= 200 always
    if (t < (int)ntot) {
      uint32 idx = (uint32)sm.hc.cand[t];
      uint32 k = (t < (int)ncand) ? kk_of(prob_one<MODE>(prow, conf, ms, b, c, (int)idx)) : 0u;
      val = ((u64)k << 32) | (uint32)(~idx);
    }
  } else {
    // ---- rare exact fallback: refine low 10 bits of kk within bucket P16-1 ----
    const uint32 BK = P16 - 1u;
    const uint32 tgt = (uint32)KK - cgA;
    for (int n = t; n < NN; n += TPB) {
      uint32 k = kk_of(prob_one<MODE>(prow, conf, ms, b, c, n));
      if (k && (k >> 10) == BK) atomicAdd(&sm.hc.hist[(k >> 5) & 31u], 1u);
    }
    __syncthreads();
    uint32 q0, d0, px, tx;
    scan_find(sm, tgt, t, lane, wv, q0, d0, px, tx);
    for (int n = t; n < NN; n += TPB) {
      uint32 k = kk_of(prob_one<MODE>(prow, conf, ms, b, c, n));
      if (k && (k >> 5) == ((BK << 5) | q0)) atomicAdd(&sm.hc.hist[k & 31u], 1u);
    }
    __syncthreads();
    uint32 q1, d1, py, ty;
    scan_find(sm, tgt - d0, t, lane, wv, q1, d1, py, ty);
    const uint32 T = (BK << 10) | (q0 << 5) | q1;
    const uint32 cnt_gt = cgA + d0 + d1;
    const uint32 m_need = (uint32)KK - cnt_gt;
    sm.hc.cand[t] = 0ull;           // hist fully dead from here on
    if (t == 0) sm.slot = 0u;
    __syncthreads();
    const int base = t * CH;
    const int endn = (base + CH < NN) ? (base + CH) : NN;
    uint32 cnteq = 0;
    for (int n = base; n < endn; ++n) {
      uint32 k = kk_of(prob_one<MODE>(prow, conf, ms, b, c, n));
      if (k > T) {
        uint32 s = atomicAdd(&sm.slot, 1u);
        sm.hc.cand[s] = ((u64)k << 32) | (uint32)(~(uint32)n);
      }
      cnteq += (k == T);
    }
    uint32 incl = cnteq;
    for (int off = 1; off < 64; off <<= 1) {
      uint32 v = __shfl_up(incl, off, 64);
      if (lane >= off) incl += v;
    }
    if (lane == 63) sm.sc4[wv] = incl;
    __syncthreads();
    uint32 add = 0;
    for (int w2 = 0; w2 < wv; ++w2) add += sm.sc4[w2];
    uint32 g = add + incl - cnteq;
    if (cnteq && g < m_need) {
      for (int n = base; n < endn && g < m_need; ++n) {
        uint32 k = kk_of(prob_one<MODE>(prow, conf, ms, b, c, n));
        if (k == T) {
          sm.hc.cand[cnt_gt + g] = ((u64)T << 32) | (uint32)(~(uint32)n);
          ++g;
        }
      }
    }
    __syncthreads();
    val = sm.hc.cand[t];
  }

  // ---- bitonic sort 256 in registers (key desc, idx asc) ----
  for (int kk = 2; kk <= 256; kk <<= 1) {
    for (int j = kk >> 1; j > 0; j >>= 1) {
      u64 other;
      if (j >= 64) {
        __syncthreads();
        sm.hc.cand[t] = val;
        __syncthreads();
        other = sm.hc.cand[t ^ j];
      } else {
        other = __shfl_xor((unsigned long long)val, j, 64);
      }
      const bool takeMax = ((t & kk) == 0) == ((t & j) == 0);
      val = takeMax ? (val > other ? val : other) : (val < other ? val : other);
    }
  }
  __syncthreads();  // s16/nms union: drain last select-phase reads before decode writes

  // ---- gather + decode (exact reference fp32 op order; guarded fexp) ----
  if (t < KK) {
    uint32 k32 = (uint32)(val >> 32);
    uint32 idx = ~((uint32)val);
    bool valid = k32 != 0u;
    float score = valid ? __uint_as_float(k32 + KBIAS) : -1.0f;
    const float4 lc = ((const float4*)loc)[(size_t)b * NN + idx];
    const float4 db = ((const float4*)dbox)[idx];
    float cx = db.x + (lc.x * 0.1f) * db.z;
    float cy = db.y + (lc.y * 0.1f) * db.w;
    float w_ = db.z * exp_f32_exact(lc.z * 0.2f);
    float h_ = db.w * exp_f32_exact(lc.w * 0.2f);
    float x1 = cx - w_ * 0.5f;
    float y1 = cy - h_ * 0.5f;
    float x2 = x1 + w_;
    float y2 = y1 + h_;
    sm.u.nms.bx1[t] = x1;
    sm.u.nms.by1[t] = y1;
    sm.u.nms.bx2[t] = x2;
    sm.u.nms.by2[t] = y2;
    sm.u.nms.barea[t] = (x2 - x1) * (y2 - y1);
    sm.u.nms.bscore[t] = score;
  } else {
    sm.u.nms.bscore[t] = -1.0f;
  }
  __syncthreads();

  // ---- IoU mask: 672 uniform 32-col units + 200 short units over all threads ----
  // chunk c covers cols [32c,32c+32), rows 0..32(c+1)-1; offset[c]=16c(c+1).
  // Per-lane load: 2-3 full units (64-96 j) + short (8 j) -> max 104 j.
  {
    // round 1: u = t in [0,256)
    {
      int u = t;
      int cq = (u >= 192) ? ((u >= 480) ? 5 : ((u >= 320) ? 4 : 3))
                          : ((u >= 96) ? 2 : ((u >= 32) ? 1 : 0));
      int off = 16 * cq * (cq + 1);
      mask_unit32(sm.u.nms, u - off, cq);
    }
    // round 2: u = 256 + t in [256,512)
    {
      int u = 256 + t;
      int cq = (u >= 480) ? 5 : ((u >= 320) ? 4 : 3);
      int off = 16 * cq * (cq + 1);
      mask_unit32(sm.u.nms, u - off, cq);
    }
    // round 3: u = 512 + t in [512,672) for t < 160 (all chunk 5)
    if (t < 160) {
      int u = 512 + t;
      mask_unit32(sm.u.nms, u - 480, 5);
    }
    if (t < KK) mask_unit_short(sm.u.nms, t);
  }
  __syncthreads();

  // ---- greedy walk on wave 0: b128 mask reads; rfl64 only on KEPT steps ----
  if (wv == 0) {
    u64 s0 = __ballot(!(sm.u.nms.bscore[lane] > 0.01f));
    u64 s1 = __ballot(!(sm.u.nms.bscore[64 + lane] > 0.01f));
    u64 s2 = __ballot(!(sm.u.nms.bscore[128 + lane] > 0.01f));
    u64 s3 = __ballot(!(sm.u.nms.bscore[192 + lane] > 0.01f)) | ~0xFFull;
    u64 k0 = 0, k1 = 0, k2 = 0, k3 = 0;
    const u64(*M)[4] = sm.u.nms.mask;
    u64 pre[4][4];   // 4-deep VGPR ring (b128 pairs); rfl at consume time
#pragma unroll
    for (int s = 0; s < 4; ++s) {
      ulonglong2 a = ((const ulonglong2*)M[s])[0];
      ulonglong2 bb = ((const ulonglong2*)M[s])[1];
      pre[s][0] = a.x; pre[s][1] = a.y; pre[s][2] = bb.x; pre[s][3] = bb.y;
    }
    // prefetch reads past row 199 stay inside the union (garbage, never consumed)
#define WALK_BLOCK(SW, KW, CNT, IBASE)                                   \
  _Pragma("unroll 4")                                                    \
  for (int ii = 0; ii < (CNT); ++ii) {                                   \
    const int s = ii & 3;                                                \
    u64 bm = 1ull << ii;                                                 \
    if (!((SW) & bm)) {                                                  \
      (KW) |= bm;                                                        \
      s0 |= rfl64(pre[s][0]); s1 |= rfl64(pre[s][1]);                    \
      s2 |= rfl64(pre[s][2]); s3 |= rfl64(pre[s][3]);                    \
    }                                                                    \
    const int inext = (IBASE) + ii + 4;                                  \
    ulonglong2 na = ((const ulonglong2*)M[inext])[0];                    \
    ulonglong2 nb = ((const ulonglong2*)M[inext])[1];                    \
    pre[s][0] = na.x; pre[s][1] = na.y; pre[s][2] = nb.x; pre[s][3] = nb.y; \
  }
    WALK_BLOCK(s0, k0, 64, 0)
    WALK_BLOCK(s1, k1, 64, 64)
    WALK_BLOCK(s2, k2, 64, 128)
    WALK_BLOCK(s3, k3, 8, 192)
#undef WALK_BLOCK
    if (lane == 0) {
      sm.u.nms.kept[0] = k0; sm.u.nms.kept[1] = k1;
      sm.u.nms.kept[2] = k2; sm.u.nms.kept[3] = k3;
    }
  } else {
    // waves 1-3: zero the whole (b,c) output slab in the walk's shadow
    float4 z4 = make_float4(0.f, 0.f, 0.f, 0.f);
    float4* o4 = (float4*)(out + outbase);          // 1000 floats = 250 float4
    for (int i = t - 64; i < (KK * 5) / 4; i += 192) o4[i] = z4;
  }
  __syncthreads();

  // ---- compacted output (kept rows only; rest pre-zeroed) ----
  if (t < KK) {
    const u64 K0 = sm.u.nms.kept[0], K1 = sm.u.nms.kept[1];
    const u64 K2 = sm.u.nms.kept[2], K3 = sm.u.nms.kept[3];
    const int w = t >> 6;
    const int bit = t & 63;
    u64 kw = (w == 0) ? K0 : (w == 1) ? K1 : (w == 2) ? K2 : K3;
    bool kp = (kw >> bit) & 1ull;
    if (kp) {
      u64 lowm = (bit == 0) ? 0ull : (~0ull >> (64 - bit));
      int d = __popcll(kw & lowm);
      if (w > 0) d += __popcll(K0);
      if (w > 1) d += __popcll(K1);
      if (w > 2) d += __popcll(K2);
      float* o = out + outbase + (size_t)d * 5;
      o[0] = sm.u.nms.bscore[t];
      o[1] = sm.u.nms.bx1[t];
      o[2] = sm.u.nms.by1[t];
      o[3] = sm.u.nms.bx2[t];
      o[4] = sm.u.nms.by2[t];
    }
  }
}

// ---------------- launch ----------------
extern "C" void kernel_launch(void* const* d_in, const int* in_sizes, int n_in,
                              void* d_out, int out_size, void* d_ws, size_t ws_size,
                              hipStream_t stream) {
  (void)in_sizes; (void)n_in; (void)out_size;
  const float* loc = (const float*)d_in[0];
  const float* conf = (const float*)d_in[1];
  const float* dbox = (const float*)d_in[2];
  float* out = (float*)d_out;

  const size_t needA = (size_t)BB * 20 * NN * sizeof(float);  // 178.8 MB transposed probs
  const size_t needB = (size_t)BB * NN * sizeof(double2);     // 35.8 MB {max, 1/S}
  dim3 blk(TPB);
  dim3 g1((NN + TPB - 1) / TPB, BB);
  const int g2 = BB * CC;

  if (ws_size >= needA) {
    float* probsT = (float*)d_ws;
    prep_kernel<0><<<g1, blk, 0, stream>>>(conf, probsT, nullptr);
    nms_kernel<0><<<g2, blk, 0, stream>>>(probsT, conf, nullptr, loc, dbox, out);
  } else if (ws_size >= needB) {
    double2* msp = (double2*)d_ws;
    prep_kernel<1><<<g1, blk, 0, stream>>>(conf, nullptr, msp);
    nms_kernel<1><<<g2, blk, 0, stream>>>(nullptr, conf, msp, loc, dbox, out);
  } else {
    nms_kernel<2><<<g2, blk, 0, stream>>>(nullptr, conf, nullptr, loc, dbox, out);
  }
}